// Round 10
// baseline (168.073 us; speedup 1.0000x reference)
//
#include <hip/hip_runtime.h>

// R24 = R21's 32x32x16 recast, ws COMPACTED to 72320 B (<= proven 72704),
// + R23's stagger. R21 post-mortem (revised): the correctness condition is
// k-map-independent — A-staging needs sig(slot) == nu_B(slot), which follows
// from the HW-verified C/D map (col=lane&31, row=(r&3)+8*(r>>2)+4*(l>>5))
// + pack order; sig32 (swap bits 2<->3) satisfies it and the same derivation
// reproduces the verified 16x16 sig_inv. R21's real bug: ws layout ran to
// 79488 B > ws_size (~73K): biases at 77824+ were unwritten POISON (0xAA f32
// ~ -3e-13 ~ 0) -> all biases dropped -> absmax 0.08 == bias magnitude. Fix:
// compact L1 (nonzero lanes only, 2K), L4 (8 lanes/frag, 1K), shared zero
// region (2K) for masked lanes, raw biases (1.6K). Total 72320 B.
// MFMA/iter 152 -> 76, per-FLOP -13% (m119); pack VALU + LDS unchanged.
//
// ws layout (bytes), written by nerf_stage:
//   0     : W2 A-frags, 32 x 1024  (f=i*8+ks; lane l at f*1024+l*16;
//            slot j = W2[32i+(l&31)][sig32(ks*16+(l>>5)*8+j)])
//   32768 : W3 A-frags, 32 x 1024  (same form)
//   65536 : L1 compact, 4 x 512    (frag i, lane m<32 only: 16 B at
//            65536+i*512+m*16; slot j = j<6 ? W1[(32i+m)*6+j] : 0)
//   67584 : L4 compact, 8 x 128    (frag ks, s=hi*4+m (m<4): 16 B at
//            67584+ks*128+s*16; slot j = W4[m*128+sig32(ks*16+hi*8+j)])
//   68608 : biases raw, 416 f32: b1[128]|b2[128]|b3[128]|b4pad[32]
//   70272 : zeros, 2048 B (masked-lane reads for L1 hi==1 / L4 m>=4)
// Main extras base eA = ws+65536 (laundered per iter; offsets 0..6784).

typedef __attribute__((ext_vector_type(8))) short short8;
typedef __attribute__((ext_vector_type(4))) float f32x4;
typedef __attribute__((ext_vector_type(16))) float f32x16;
typedef __attribute__((ext_vector_type(2))) float f32x2;
typedef __attribute__((ext_vector_type(4))) unsigned int u32x4;

#define MFMA32(a, b, c) __builtin_amdgcn_mfma_f32_32x32x16_bf16((a), (b), (c), 0, 0, 0)

__device__ __forceinline__ unsigned short bfr(float f) {  // fp32->bf16 RNE
  unsigned u = __builtin_bit_cast(unsigned, f);
  u += 0x7FFFu + ((u >> 16) & 1u);
  return (unsigned short)(u >> 16);
}

// (bf16(a) low16, bf16(b) high16) in ONE v_cvt_pk_bf16_f32 (R20's win).
__device__ __forceinline__ unsigned pk2(float a, float b) {
  unsigned r;
  asm("v_cvt_pk_bf16_f32 %0, %1, %2" : "=v"(r) : "v"(a), "v"(b));
  return r;
}

__device__ __forceinline__ unsigned pkrelu(float a, float b) {
  a = __builtin_fmaxf(a, 0.f);
  b = __builtin_fmaxf(b, 0.f);
  return pk2(a, b);
}

__device__ __forceinline__ short8 pack8lo(const f32x16& c) {
  u32x4 u;
  u.x = pkrelu(c[0], c[1]);
  u.y = pkrelu(c[2], c[3]);
  u.z = pkrelu(c[4], c[5]);
  u.w = pkrelu(c[6], c[7]);
  return __builtin_bit_cast(short8, u);
}

__device__ __forceinline__ short8 pack8hi(const f32x16& c) {
  u32x4 u;
  u.x = pkrelu(c[8], c[9]);
  u.y = pkrelu(c[10], c[11]);
  u.z = pkrelu(c[12], c[13]);
  u.w = pkrelu(c[14], c[15]);
  return __builtin_bit_cast(short8, u);
}

// bias rows for acc regs: reg r=4p+s needs b[32i+8p+4hi+s] -> 4x f32x4
__device__ __forceinline__ f32x16 ldbias(const char* p) {
  const f32x4 b0 = *(const f32x4*)(p);
  const f32x4 b1 = *(const f32x4*)(p + 32);
  const f32x4 b2 = *(const f32x4*)(p + 64);
  const f32x4 b3 = *(const f32x4*)(p + 96);
  f32x16 a = {b0.x, b0.y, b0.z, b0.w, b1.x, b1.y, b1.z, b1.w,
              b2.x, b2.y, b2.z, b2.w, b3.x, b3.y, b3.z, b3.w};
  return a;
}

// consumer k-slot -> producer neuron: swap bits 2 and 3
__device__ __forceinline__ int sig32(int kp) {
  return (kp & ~12) | ((kp & 4) << 1) | ((kp & 8) >> 1);
}

__global__ void nerf_stage(const float* __restrict__ W1, const float* __restrict__ b1,
                           const float* __restrict__ W2, const float* __restrict__ b2,
                           const float* __restrict__ W3, const float* __restrict__ b3,
                           const float* __restrict__ W4, const float* __restrict__ b4,
                           void* __restrict__ ws) {
  unsigned short* wf = (unsigned short*)ws;
  const int idx = blockIdx.x * 256 + threadIdx.x;
  const int stride = gridDim.x * 256;

  // W2 (f 0..31) and W3 (f 32..63) A-frags
  for (int p = idx; p < 64 * 64; p += stride) {
    const int f = p >> 6, l = p & 63, m = l & 31, hi = l >> 5;
    const int g = f & 31, i = g >> 3, ks = g & 7;
    const float* W = (f < 32) ? W2 : W3;
    unsigned short v[8];
#pragma unroll
    for (int j = 0; j < 8; ++j)
      v[j] = bfr(W[(i * 32 + m) * 128 + sig32(ks * 16 + hi * 8 + j)]);
#pragma unroll
    for (int j = 0; j < 8; ++j) wf[f * 512 + l * 8 + j] = v[j];
  }

  // L1 compact: 4 frags x 32 lanes at short 32768 (byte 65536)
  for (int e = idx; e < 128; e += stride) {
    const int i = e >> 5, m = e & 31;
    unsigned short v[8];
#pragma unroll
    for (int j = 0; j < 8; ++j)
      v[j] = (j < 6) ? bfr(W1[(i * 32 + m) * 6 + j]) : (unsigned short)0;
#pragma unroll
    for (int j = 0; j < 8; ++j) wf[32768 + i * 256 + m * 8 + j] = v[j];
  }

  // L4 compact: 8 frags x 8 slots (s = hi*4+m, m<4) at short 33792 (byte 67584)
  for (int e = idx; e < 64; e += stride) {
    const int ks = e >> 3, s = e & 7, hi = s >> 2, m = s & 3;
    unsigned short v[8];
#pragma unroll
    for (int j = 0; j < 8; ++j)
      v[j] = bfr(W4[m * 128 + sig32(ks * 16 + hi * 8 + j)]);
#pragma unroll
    for (int j = 0; j < 8; ++j) wf[33792 + ks * 64 + s * 8 + j] = v[j];
  }

  // biases raw at byte 68608: b1[128] | b2[128] | b3[128] | b4pad[32]
  {
    float* fb = (float*)((char*)ws + 68608);
    for (int e = idx; e < 416; e += stride) {
      float val;
      if (e < 128) val = b1[e];
      else if (e < 256) val = b2[e - 128];
      else if (e < 384) val = b3[e - 256];
      else val = ((e - 384) < 4) ? b4[e - 384] : 0.f;
      fb[e] = val;
    }
  }

  // zeros at byte 70272 (ws poisoned 0xAA each launch -> must clear)
  {
    float* z = (float*)((char*)ws + 70272);
    for (int e = idx; e < 512; e += stride) z[e] = 0.f;
  }
}

__launch_bounds__(1024, 4)
__global__ void nerf_main(const float* __restrict__ x, float* __restrict__ out,
                          const void* __restrict__ ws, int nGroups) {
  __shared__ __align__(16) unsigned short lds[32768];  // exactly 65536 B: W2 | W3

  {  // copy W2/W3 frags only: 65536/16 = 4096 16B chunks
    const u32x4* src = (const u32x4*)ws;
    u32x4* dst = (u32x4*)lds;
    for (int i = threadIdx.x; i < 4096; i += 1024) dst[i] = src[i];
  }
  __syncthreads();

  const int lane = threadIdx.x & 63;
  const int wid = threadIdx.x >> 6;  // 0..15
  const int hi = lane >> 5;          // k-half
  const int m = lane & 31;           // A row / B col (batch item)

  // ---- phase stagger (R23: +4.5%): de-convoy the 4 waves/SIMD ----
  {
    const int ws4 = wid & 3;
    if (ws4 == 1) __builtin_amdgcn_s_sleep(8);
    else if (ws4 == 2) __builtin_amdgcn_s_sleep(16);
    else if (ws4 == 3) __builtin_amdgcn_s_sleep(24);
  }

  const int waveId = blockIdx.x * 16 + wid;
  const int totalWaves = gridDim.x * 16;

  const unsigned short* w2l = lds + lane * 8;            // + (i*8+ks)*512
  const unsigned short* w3l = lds + 16384 + lane * 8;    // + (i*8+ks)*512

  // lane-conditional extras offsets rel. to eA = ws+65536 (masked lanes ->
  // zeros region [4736,6784); strides i*512 / ks*128 stay inside it)
  const int l1off = ((hi == 0) ? 0 : 4736) + m * 16;                    // + i*512
  const int l4off = (m < 4) ? (2048 + (hi * 4 + m) * 16) : (4736 + m * 16);  // + ks*128
  const int bOff = 3072 + hi * 16;  // + layer*512 + i*128

  float px[6];
  int g = waveId;
  if (g < nGroups && hi == 0) {
    const float* p = x + (g * 32 + m) * 6;
    f32x2 a = *(const f32x2*)p, b = *(const f32x2*)(p + 2), c = *(const f32x2*)(p + 4);
    px[0] = a.x; px[1] = a.y; px[2] = b.x; px[3] = b.y; px[4] = c.x; px[5] = c.y;
  }

  for (; g < nGroups; g += totalWaves) {
    // ---- anti-hoist: launder the extras base every iteration ----
    uintptr_t wsl = (uintptr_t)ws;
    asm volatile("" : "+v"(wsl));
    const char* eA = (const char*)wsl + 65536;
    const char* l1p = eA + l1off;
    const char* l4p = eA + l4off;
    const char* bp = eA + bOff;

    // ---- xb: one 32-col B frag (hi==0: k0..5 = x; bias via C) ----
    short8 xb;
    {
      u32x4 u = {0u, 0u, 0u, 0u};
      if (hi == 0) {
        u.x = pk2(px[0], px[1]);
        u.y = pk2(px[2], px[3]);
        u.z = pk2(px[4], px[5]);
      }
      xb = __builtin_bit_cast(short8, u);
    }
    const int gn = g + totalWaves;
    if (gn < nGroups && hi == 0) {
      const float* p = x + (gn * 32 + m) * 6;
      f32x2 a = *(const f32x2*)p, b = *(const f32x2*)(p + 2), c = *(const f32x2*)(p + 4);
      px[0] = a.x; px[1] = a.y; px[2] = b.x; px[3] = b.y; px[4] = c.x; px[5] = c.y;
    }

    short8 B1f[8], B2f[8];

    // ---- layer 1: 4 MFMA (K=16), bias as C from b1 ----
#pragma unroll
    for (int i = 0; i < 4; ++i) {
      const short8 w = *(const short8*)(l1p + i * 512);
      f32x16 acc = ldbias(bp + i * 128);
      acc = MFMA32(w, xb, acc);
      B1f[2 * i] = pack8lo(acc);
      B1f[2 * i + 1] = pack8hi(acc);
    }

    // ---- layer 2: 4 tiles x 8 k-steps from LDS, bias b2 ----
#pragma unroll
    for (int i = 0; i < 4; ++i) {
      f32x16 acc = ldbias(bp + 512 + i * 128);
#pragma unroll
      for (int ks = 0; ks < 8; ++ks)
        acc = MFMA32(*(const short8*)(w2l + (i * 8 + ks) * 512), B1f[ks], acc);
      B2f[2 * i] = pack8lo(acc);
      B2f[2 * i + 1] = pack8hi(acc);
    }

    // ---- layer 3: same with W3, bias b3 -> B1f ----
#pragma unroll
    for (int i = 0; i < 4; ++i) {
      f32x16 acc = ldbias(bp + 1024 + i * 128);
#pragma unroll
      for (int ks = 0; ks < 8; ++ks)
        acc = MFMA32(*(const short8*)(w3l + (i * 8 + ks) * 512), B2f[ks], acc);
      B1f[2 * i] = pack8lo(acc);
      B1f[2 * i + 1] = pack8hi(acc);
    }

    // ---- layer 4: 8 k-steps from global compact frags, bias b4pad ----
    {
      f32x16 acc = ldbias(bp + 1536);
#pragma unroll
      for (int ks = 0; ks < 8; ++ks)
        acc = MFMA32(*(const short8*)(l4p + ks * 128), B1f[ks], acc);
      if (hi == 0) {
        f32x4 o = {acc[0], acc[1], acc[2], acc[3]};
        *(f32x4*)(out + (g * 32 + m) * 4) = o;
      }
    }
  }
}

extern "C" void kernel_launch(void* const* d_in, const int* in_sizes, int n_in,
                              void* d_out, int out_size, void* d_ws, size_t ws_size,
                              hipStream_t stream) {
  const float* x  = (const float*)d_in[0];
  const float* W1 = (const float*)d_in[1];
  const float* b1 = (const float*)d_in[2];
  const float* W2 = (const float*)d_in[3];
  const float* b2 = (const float*)d_in[4];
  const float* W3 = (const float*)d_in[5];
  const float* b3 = (const float*)d_in[6];
  const float* W4 = (const float*)d_in[7];
  const float* b4 = (const float*)d_in[8];
  float* out = (float*)d_out;

  const int N = in_sizes[0] / 6;
  const int nGroups = N / 32;  // one 32-row MFMA B-tile per wave-iteration

  nerf_stage<<<dim3(4), dim3(256), 0, stream>>>(W1, b1, W2, b2, W3, b3, W4, b4, d_ws);

  // 512 blocks x 16 waves; regs cap residency at 16 waves/CU (4/SIMD).
  nerf_main<<<dim3(512), dim3(1024), 0, stream>>>(x, out, d_ws, nGroups);
}

// Round 11
// 154.631 us; speedup vs baseline: 1.0869x; 1.0869x over previous
//
#include <hip/hip_runtime.h>

// R25 = R23 (83.5 us best: 16x16x32, cvt_pk pack, stagger) + two adds:
//  (a) s_setprio(1/0) around each MFMA cluster. R17's setprio was confounded
//      by its mov-heavy manual pipeline; T5 is null in lockstep but pays with
//      phase diversity — which R23's stagger now provides. Pure addition.
//  (b) nerf_stage grid 4 -> 32 blocks: stage is latency-bound scattered
//      reads on 4 CUs, serial before main; grid-stride makes it a 1-liner.
// R24 post-mortem: 32x32 recast now CORRECT (ws-overflow theory confirmed)
// but 100 us vs 83.5: VGPR pinned at 64 + FETCH +1.6/WRITE +5.2 MB = spill.
// B1f+B2f(64) + f32x16 acc(16) + addr ~= 85 regs > the 64 ceiling that
// 1024-thr blocks force (16 waves/4 SIMDs). 32x32 path dead at this shape.
//
// ws layout (bytes) — written by nerf_stage (same as R12..R20):
//   0     : W2 frags, 32 x 1024   (f = ks*8+nt; lane l at f*1024 + l*16)
//   32768 : W3 frags, 32 x 1024
//   65536 : L1 compact, 8 x 256   (frag nt, slot n: j<6 -> W1[(nt*16+n)*6+j],
//                                  j==6 -> b1[nt*16+n], j==7 -> 0)
//   67584 : L4 compact, 4 x 256   (frag ks, slot s=q*4+outrow)
//   68608 : zeros, 2048
//   70656 : bias2 = b2[0..127]    (f32x4 entry nt*4+q)
//   71168 : bias3 = b3[0..127]
//   71680 : b4 padded (q==0 -> b4[0..3], else 0)

typedef __attribute__((ext_vector_type(8))) short short8;
typedef __attribute__((ext_vector_type(4))) float f32x4;
typedef __attribute__((ext_vector_type(2))) float f32x2;
typedef __attribute__((ext_vector_type(4))) unsigned int u32x4;

#define MFMA(a, b, c) __builtin_amdgcn_mfma_f32_16x16x32_bf16((a), (b), (c), 0, 0, 0)

__device__ __forceinline__ unsigned short bfr(float f) {  // fp32->bf16 RNE
  unsigned u = __builtin_bit_cast(unsigned, f);
  u += 0x7FFFu + ((u >> 16) & 1u);
  return (unsigned short)(u >> 16);
}

// (bf16(a) low16, bf16(b) high16) in ONE v_cvt_pk_bf16_f32 (R20's win).
__device__ __forceinline__ unsigned pk2(float a, float b) {
  unsigned r;
  asm("v_cvt_pk_bf16_f32 %0, %1, %2" : "=v"(r) : "v"(a), "v"(b));
  return r;
}

__device__ __forceinline__ unsigned pkrelu(float a, float b) {
  a = __builtin_fmaxf(a, 0.f);
  b = __builtin_fmaxf(b, 0.f);
  return pk2(a, b);
}

__device__ __forceinline__ short8 pack4(const f32x4& a0, const f32x4& a1) {
  u32x4 u;
  u.x = pkrelu(a0.x, a0.y);
  u.y = pkrelu(a0.z, a0.w);
  u.z = pkrelu(a1.x, a1.y);
  u.w = pkrelu(a1.z, a1.w);
  return __builtin_bit_cast(short8, u);
}

// consumer B k-slot kp <- producer neuron slot sig_inv(kp)
__device__ __forceinline__ int sig_inv(int kp) {
  return ((kp >> 5) << 5) + (((kp >> 2) & 1) << 4) + (((kp >> 3) & 3) << 2) + (kp & 3);
}

__global__ void nerf_stage(const float* __restrict__ W1, const float* __restrict__ b1,
                           const float* __restrict__ W2, const float* __restrict__ b2,
                           const float* __restrict__ W3, const float* __restrict__ b3,
                           const float* __restrict__ W4, const float* __restrict__ b4,
                           void* __restrict__ ws) {
  unsigned short* wf = (unsigned short*)ws;
  const int idx = blockIdx.x * 256 + threadIdx.x;
  const int stride = gridDim.x * 256;

  // W2 (f 0..31) and W3 (f 32..63) full frags
  for (int p = idx; p < 64 * 64; p += stride) {
    const int f = p >> 6, l = p & 63, m = l & 15, q = l >> 4;
    const int g = f & 31, ks = g >> 3, nt = g & 7;
    const float* W = (f < 32) ? W2 : W3;
    unsigned short v[8];
#pragma unroll
    for (int j = 0; j < 8; ++j)
      v[j] = bfr(W[(nt * 16 + m) * 128 + sig_inv(ks * 32 + q * 8 + j)]);
#pragma unroll
    for (int j = 0; j < 8; ++j) wf[f * 512 + l * 8 + j] = v[j];
  }

  // L1 compact: 8 frags x 16 slots at byte 65536
  for (int e = idx; e < 128; e += stride) {
    const int nt = e >> 4, n = e & 15;
    unsigned short v[8];
#pragma unroll
    for (int j = 0; j < 8; ++j) {
      float val = 0.f;
      if (j < 6) val = W1[(nt * 16 + n) * 6 + j];
      else if (j == 6) val = b1[nt * 16 + n];
      v[j] = bfr(val);
    }
#pragma unroll
    for (int j = 0; j < 8; ++j) wf[(65536 >> 1) + e * 8 + j] = v[j];
  }

  // L4 compact: 4 frags x 16 slots (s = q*4 + outrow) at byte 67584
  for (int e = idx; e < 64; e += stride) {
    const int ks = e >> 4, s = e & 15, q = s >> 2, n = s & 3;
    unsigned short v[8];
#pragma unroll
    for (int j = 0; j < 8; ++j)
      v[j] = bfr(W4[n * 128 + sig_inv(ks * 32 + q * 8 + j)]);
#pragma unroll
    for (int j = 0; j < 8; ++j) wf[(67584 >> 1) + e * 8 + j] = v[j];
  }

  // zeros at byte 68608 (ws is poisoned 0xAA each launch -> must clear)
  {
    float* z = (float*)((char*)ws + 68608);
    for (int e = idx; e < 512; e += stride) z[e] = 0.f;
  }

  // biases at byte 70656: b2 | b3 | b4 padded
  {
    float* wb = (float*)((char*)ws + 70656);
    for (int e = idx; e < 272; e += stride) {
      float val;
      if (e < 128) val = b2[e];
      else if (e < 256) val = b3[e - 128];
      else val = ((e & 15) < 4) ? b4[e & 3] : 0.f;
      wb[e] = val;
    }
  }
}

__launch_bounds__(1024, 4)
__global__ void nerf_main(const float* __restrict__ x, float* __restrict__ out,
                          const void* __restrict__ ws, int nGroups) {
  __shared__ __align__(16) unsigned short lds[32768];  // exactly 65536 B: W2 | W3

  {  // copy W2/W3 frags only: 65536/16 = 4096 16B chunks
    const u32x4* src = (const u32x4*)ws;
    u32x4* dst = (u32x4*)lds;
    for (int i = threadIdx.x; i < 4096; i += 1024) dst[i] = src[i];
  }
  __syncthreads();

  const int lane = threadIdx.x & 63;
  const int wid = threadIdx.x >> 6;  // 0..15
  const int q = lane >> 4;
  const int n = lane & 15;

  // ---- phase stagger (R23: +4.5%): de-convoy the 4 waves/SIMD ----
  {
    const int ws4 = wid & 3;
    if (ws4 == 1) __builtin_amdgcn_s_sleep(8);        // ~512 cyc
    else if (ws4 == 2) __builtin_amdgcn_s_sleep(16);  // ~1024 cyc
    else if (ws4 == 3) __builtin_amdgcn_s_sleep(24);  // ~1536 cyc
  }

  const int waveId = blockIdx.x * 16 + wid;
  const int totalWaves = gridDim.x * 16;

  // LDS bases (frag index in the offset)
  const unsigned short* w2b = lds + lane * 8;            // + (ks*8+nt)*512
  const unsigned short* w3b = lds + 16384 + lane * 8;    // + (ks*8+nt)*512

  // lane-conditional byte offsets for the extras (bases derived per-iteration
  // from the laundered pointer so the loads cannot be hoisted out of the loop)
  const int l1off = ((q == 0) ? 65536 : 68608) + n * 16;
  const int l4off = (n < 4) ? (67584 + (q * 4 + n) * 16) : (68608 + n * 16);
  const int b2off = 70656 + q * 16;
  const int b3off = 71168 + q * 16;
  const int b4off = 71680 + q * 16;

  const f32x4 zf = {0.f, 0.f, 0.f, 0.f};

  float px[2][6] = {};
  int g = waveId;
  if (g < nGroups && q == 0) {
#pragma unroll
    for (int t = 0; t < 2; ++t) {
      const float* p = x + (g * 32 + t * 16 + n) * 6;
      f32x2 a = *(const f32x2*)p, b = *(const f32x2*)(p + 2), c = *(const f32x2*)(p + 4);
      px[t][0] = a.x; px[t][1] = a.y; px[t][2] = b.x;
      px[t][3] = b.y; px[t][4] = c.x; px[t][5] = c.y;
    }
  }

  for (; g < nGroups; g += totalWaves) {
    // ---- anti-hoist: launder the extras base every iteration ----
    uintptr_t wsl = (uintptr_t)ws;
    asm volatile("" : "+v"(wsl));  // opaque -> extras loads stay in the loop
    const char* wsv = (const char*)wsl;
    const short8* l1g = (const short8*)(wsv + l1off);   // + nt*16
    const short8* l4g = (const short8*)(wsv + l4off);   // + ks*16
    const f32x4* bias2 = (const f32x4*)(wsv + b2off);   // + nt*4
    const f32x4* bias3 = (const f32x4*)(wsv + b3off);   // + nt*4
    const f32x4* b4p   = (const f32x4*)(wsv + b4off);

    // ---- x -> layer-1 B frags (q==0: k0..5 = x, k6 = 1.0 bias slot) ----
    short8 xb[2];
#pragma unroll
    for (int t = 0; t < 2; ++t) {
      u32x4 u = {0u, 0u, 0u, 0u};
      if (q == 0) {
        u.x = pk2(px[t][0], px[t][1]);
        u.y = pk2(px[t][2], px[t][3]);
        u.z = pk2(px[t][4], px[t][5]);
        u.w = 0x00003F80u;  // elem6 = bf16 1.0, elem7 = 0
      }
      xb[t] = __builtin_bit_cast(short8, u);
    }
    const int gn = g + totalWaves;
    if (gn < nGroups && q == 0) {
#pragma unroll
      for (int t = 0; t < 2; ++t) {
        const float* p = x + (gn * 32 + t * 16 + n) * 6;
        f32x2 a = *(const f32x2*)p, b = *(const f32x2*)(p + 2), c = *(const f32x2*)(p + 4);
        px[t][0] = a.x; px[t][1] = a.y; px[t][2] = b.x;
        px[t][3] = b.y; px[t][4] = c.x; px[t][5] = c.y;
      }
    }

    short8 B1[2][4], B2[2][4];

    // ---- layer 1 (compact frags from global/L2; bias in k-slot 6; C=0) ----
#pragma unroll
    for (int ntp = 0; ntp < 4; ++ntp) {
      const short8 w0 = l1g[(2 * ntp) * 16];
      const short8 w1 = l1g[(2 * ntp + 1) * 16];
      f32x4 a0[2], a1[2];
      __builtin_amdgcn_s_setprio(1);
#pragma unroll
      for (int t = 0; t < 2; ++t) {
        a0[t] = MFMA(w0, xb[t], zf);
        a1[t] = MFMA(w1, xb[t], zf);
      }
      __builtin_amdgcn_s_setprio(0);
#pragma unroll
      for (int t = 0; t < 2; ++t) B1[t][ntp] = pack4(a0[t], a1[t]);
    }

    // ---- layer 2 (W2 frags from LDS; bias as C at ks==0) ----
#pragma unroll
    for (int ntp = 0; ntp < 4; ++ntp) {
      f32x4 a0[2], a1[2];
      __builtin_amdgcn_s_setprio(1);
#pragma unroll
      for (int ks = 0; ks < 4; ++ks) {
        const short8 w0 = *(const short8*)(w2b + (ks * 8 + 2 * ntp) * 512);
        const short8 w1 = *(const short8*)(w2b + (ks * 8 + 2 * ntp + 1) * 512);
        if (ks == 0) {
          const f32x4 bv0 = bias2[(2 * ntp) * 4];
          const f32x4 bv1 = bias2[(2 * ntp + 1) * 4];
#pragma unroll
          for (int t = 0; t < 2; ++t) {
            a0[t] = MFMA(w0, B1[t][0], bv0);
            a1[t] = MFMA(w1, B1[t][0], bv1);
          }
        } else {
#pragma unroll
          for (int t = 0; t < 2; ++t) {
            a0[t] = MFMA(w0, B1[t][ks], a0[t]);
            a1[t] = MFMA(w1, B1[t][ks], a1[t]);
          }
        }
      }
      __builtin_amdgcn_s_setprio(0);
#pragma unroll
      for (int t = 0; t < 2; ++t) B2[t][ntp] = pack4(a0[t], a1[t]);
    }

    // ---- layer 3 (W3 frags from LDS) ----
#pragma unroll
    for (int ntp = 0; ntp < 4; ++ntp) {
      f32x4 a0[2], a1[2];
      __builtin_amdgcn_s_setprio(1);
#pragma unroll
      for (int ks = 0; ks < 4; ++ks) {
        const short8 w0 = *(const short8*)(w3b + (ks * 8 + 2 * ntp) * 512);
        const short8 w1 = *(const short8*)(w3b + (ks * 8 + 2 * ntp + 1) * 512);
        if (ks == 0) {
          const f32x4 bv0 = bias3[(2 * ntp) * 4];
          const f32x4 bv1 = bias3[(2 * ntp + 1) * 4];
#pragma unroll
          for (int t = 0; t < 2; ++t) {
            a0[t] = MFMA(w0, B2[t][0], bv0);
            a1[t] = MFMA(w1, B2[t][0], bv1);
          }
        } else {
#pragma unroll
          for (int t = 0; t < 2; ++t) {
            a0[t] = MFMA(w0, B2[t][ks], a0[t]);
            a1[t] = MFMA(w1, B2[t][ks], a1[t]);
          }
        }
      }
      __builtin_amdgcn_s_setprio(0);
#pragma unroll
      for (int t = 0; t < 2; ++t) B1[t][ntp] = pack4(a0[t], a1[t]);  // reuse B1
    }

    // ---- layer 4 (compact frags from global/L2; out rows at q==0) ----
    f32x4 o[2];
    {
      const f32x4 bv = b4p[0];
      __builtin_amdgcn_s_setprio(1);
#pragma unroll
      for (int ks = 0; ks < 4; ++ks) {
        const short8 w = l4g[ks * 16];
        if (ks == 0) {
#pragma unroll
          for (int t = 0; t < 2; ++t) o[t] = MFMA(w, B1[t][0], bv);
        } else {
#pragma unroll
          for (int t = 0; t < 2; ++t) o[t] = MFMA(w, B1[t][ks], o[t]);
        }
      }
      __builtin_amdgcn_s_setprio(0);
    }
    if (q == 0) {
#pragma unroll
      for (int t = 0; t < 2; ++t)
        *(f32x4*)(out + (g * 32 + t * 16 + n) * 4) = o[t];
    }
  }
}

extern "C" void kernel_launch(void* const* d_in, const int* in_sizes, int n_in,
                              void* d_out, int out_size, void* d_ws, size_t ws_size,
                              hipStream_t stream) {
  const float* x  = (const float*)d_in[0];
  const float* W1 = (const float*)d_in[1];
  const float* b1 = (const float*)d_in[2];
  const float* W2 = (const float*)d_in[3];
  const float* b2 = (const float*)d_in[4];
  const float* W3 = (const float*)d_in[5];
  const float* b3 = (const float*)d_in[6];
  const float* W4 = (const float*)d_in[7];
  const float* b4 = (const float*)d_in[8];
  float* out = (float*)d_out;

  const int N = in_sizes[0] / 6;
  const int nGroups = N / 32;  // 2 tiles of 16 rows per wave-iteration -> 32768

  // Stage widened 4 -> 32 blocks: latency-bound scattered reads, serial
  // before main; grid-stride loops make this purely parallelizing.
  nerf_stage<<<dim3(32), dim3(256), 0, stream>>>(W1, b1, W2, b2, W3, b3, W4, b4, d_ws);

  // 512 blocks x 16 waves; regs cap residency at 16 waves/CU (4/SIMD).
  nerf_main<<<dim3(512), dim3(1024), 0, stream>>>(x, out, d_ws, nGroups);
}